// Round 1
// 136.981 us; speedup vs baseline: 1.0138x; 1.0138x over previous
//
#include <hip/hip_runtime.h>

// out[b,h] = sum_{i,j} cb[h, i*64+j] * in1[b,i] * in2[b,j]
// B = 4096, dim1 = dim2 = 64, H = 4096.
//
// Round-8 = round-7 (float2 batch packing, pair fusion) with the cb-value
// broadcast path rebuilt: table rows are wave-uniform, so they are loaded
// into SGPRs via inline-asm s_load_dwordx16 and consumed directly as SGPR
// operands of the packed FMAs. This deletes all v_readlane instructions
// (~45% of inner-loop issue) and their VALU->SGPR hazard stalls.
// Table layout (prep_kernel) is unchanged: row h = n1*n2 packed floats.

typedef float vf2 __attribute__((ext_vector_type(2)));
typedef int   si16 __attribute__((ext_vector_type(16)));

#define SDIM 65   // s1v/s2v row stride in float2 units
#define SOH  17   // so row stride (h-minor, odd -> 2-way banks on writes)

__constant__ int   kStart[7] = {0, 64, 496, 1376, 2496, 3360, 3888};
__constant__ unsigned kMagic[7] = {262144u, 87382u, 52429u, 37450u, 29128u, 23832u, 20165u}; // 2^18/d rounded up, d=2*l3+1
__constant__ int   kVpOff[7] = {0, 4, 13, 24, 34, 40, 43};
__constant__ unsigned char kVp[44] = {
  0, 5, 10, 15,                                  // l3=0
  1, 4, 5, 6, 9, 10, 11, 14, 15,                 // l3=1
  2, 5, 6, 7, 8, 9, 10, 11, 13, 14, 15,          // l3=2 ((1,3) before (2,0))
  3, 6, 7, 9, 10, 11, 12, 13, 14, 15,            // l3=3 ((2,3) before (3,0))
  7, 10, 11, 13, 14, 15,                         // l3=4
  11, 14, 15,                                    // l3=5
  15};                                           // l3=6
__constant__ int kBase[4] = {0, 4, 16, 36};  // offset of first slot of each l

__device__ __forceinline__ void decode_h(int h, int& i1, int& i2,
                                         int& n1, int& n2, int& l1l2) {
  int l3 = (h >= 64) + (h >= 496) + (h >= 1376) + (h >= 2496) + (h >= 3360) + (h >= 3888);
  unsigned hl = (unsigned)(h - kStart[l3]);
  int pair = (int)((hl * kMagic[l3]) >> 18);   // hl / (2*l3+1), exact in range
  int slot = pair & 15;
  int vp   = pair >> 4;
  l1l2 = (int)kVp[kVpOff[l3] + vp];
  int l1 = l1l2 >> 2, l2 = l1l2 & 3;
  n1 = 2 * l1 + 1;
  n2 = 2 * l2 + 1;
  i1 = kBase[l1] + (slot >> 2) * n1;
  i2 = kBase[l2] + (slot & 3) * n2;
}

// ---- prep: compact cb rows + decode metadata (layout unchanged) ----
__global__ __launch_bounds__(256) void prep_kernel(const float* __restrict__ cb,
                                                   float* __restrict__ table,
                                                   int* __restrict__ meta) {
  int idx = blockIdx.x * 256 + threadIdx.x;   // 1024 blocks -> 262144 = 4096*64
  int h = idx >> 6, e = idx & 63;
  int i1, i2, n1, n2, c;
  decode_h(h, i1, i2, n1, n2, c);
  if (e == 0) meta[h] = i1 | (i2 << 8) | (c << 16);
  unsigned mg = (n2 == 1) ? 65536u : (n2 == 3) ? 21846u : (n2 == 5) ? 13108u : 9363u;
  int qi = (int)(((unsigned)e * mg) >> 16);   // e / n2, exact for e < 64
  int rj = e - qi * n2;
  float v = 0.f;
  if (e < n1 * n2) v = cb[(size_t)h * 4096 + (i1 + qi) * 64 + (i2 + rj)];
  table[(size_t)h * 64 + e] = v;
}

__device__ __forceinline__ vf2 splat(float c) { vf2 r; r.x = c; r.y = c; return r; }

// ---- wave-uniform SGPR loads of the cb row ----
template <int IMM>
__device__ __forceinline__ si16 sload16(unsigned long long base) {
  si16 r;
  asm volatile("s_load_dwordx16 %0, %1, %2" : "=s"(r) : "s"(base), "i"(IMM));
  return r;
}

// waitcnt + scheduling fence (rule 18: keep SGPR consumers below the wait)
__device__ __forceinline__ void swait() {
  asm volatile("s_waitcnt lgkmcnt(0)" ::: "memory");
  __builtin_amdgcn_sched_barrier(0);
}

template <int IDX>
__device__ __forceinline__ float cget(si16 c0, si16 c1, si16 c2, si16 c3) {
  if constexpr (IDX < 16)      return __int_as_float(c0[IDX & 15]);
  else if constexpr (IDX < 32) return __int_as_float(c1[IDX & 15]);
  else if constexpr (IDX < 48) return __int_as_float(c2[IDX & 15]);
  else                         return __int_as_float(c3[IDX & 15]);
}

// one cb row (byte address rowB, wave-uniform), 2 batches packed per lane
template <int N1, int N2>
__device__ __forceinline__ vf2 row_compute(unsigned long long rowB,
                                           const vf2* __restrict__ aa,
                                           const vf2* __restrict__ bb) {
  constexpr int CNT = N1 * N2;   // <= 49, row stride is 64 floats (256 B)
  si16 c0, c1, c2, c3;
  c0 = sload16<0>(rowB);
  if constexpr (CNT > 16) c1 = sload16<64>(rowB);
  if constexpr (CNT > 32) c2 = sload16<128>(rowB);
  if constexpr (CNT > 48) c3 = sload16<192>(rowB);
  swait();
  vf2 acc0 = splat(0.f), acc1 = splat(0.f);
  vf2 t = splat(0.f);
#define RC_STEP(IDX)                                                          \
  if constexpr ((IDX) < CNT) {                                                \
    constexpr int ri = (IDX) / N2, rj = (IDX) % N2;                           \
    float v = cget<(IDX)>(c0, c1, c2, c3);                                    \
    if constexpr (rj == 0) t = splat(v) * bb[0];                              \
    else t = __builtin_elementwise_fma(splat(v), bb[rj], t);                  \
    if constexpr (rj == N2 - 1) {                                             \
      if constexpr ((ri & 1) == 1)                                            \
        acc1 = __builtin_elementwise_fma(aa[ri], t, acc1);                    \
      else                                                                    \
        acc0 = __builtin_elementwise_fma(aa[ri], t, acc0);                    \
    }                                                                         \
  }
  RC_STEP(0)  RC_STEP(1)  RC_STEP(2)  RC_STEP(3)  RC_STEP(4)  RC_STEP(5)
  RC_STEP(6)  RC_STEP(7)  RC_STEP(8)  RC_STEP(9)  RC_STEP(10) RC_STEP(11)
  RC_STEP(12) RC_STEP(13) RC_STEP(14) RC_STEP(15) RC_STEP(16) RC_STEP(17)
  RC_STEP(18) RC_STEP(19) RC_STEP(20) RC_STEP(21) RC_STEP(22) RC_STEP(23)
  RC_STEP(24) RC_STEP(25) RC_STEP(26) RC_STEP(27) RC_STEP(28) RC_STEP(29)
  RC_STEP(30) RC_STEP(31) RC_STEP(32) RC_STEP(33) RC_STEP(34) RC_STEP(35)
  RC_STEP(36) RC_STEP(37) RC_STEP(38) RC_STEP(39) RC_STEP(40) RC_STEP(41)
  RC_STEP(42) RC_STEP(43) RC_STEP(44) RC_STEP(45) RC_STEP(46) RC_STEP(47)
  RC_STEP(48)
#undef RC_STEP
  // keep the next row's 64-SGPR chunk set from going live during this
  // row's compute (SGPR-pressure guard; avoids spills in the N1*N2=49 case)
  __builtin_amdgcn_sched_barrier(0);
  return acc0 + acc1;
}

// single row, 2 batches packed
template <int N1, int N2>
__device__ __forceinline__ vf2 inner_tp_s(unsigned long long rowB,
                                          const vf2* __restrict__ s1r,
                                          const vf2* __restrict__ s2r,
                                          int i1, int i2) {
  vf2 bb[N2], aa[N1];
#pragma unroll
  for (int j = 0; j < N2; ++j) bb[j] = s2r[i2 + j];
#pragma unroll
  for (int i = 0; i < N1; ++i) aa[i] = s1r[i1 + i];
  return row_compute<N1, N2>(rowB, aa, bb);
}

// fused same-run pair x 2 batches: aa/bb loaded once for both rows
template <int N1, int N2>
__device__ __forceinline__ void inner_tp2_s(unsigned long long rowB,
                                            const vf2* __restrict__ s1r,
                                            const vf2* __restrict__ s2r,
                                            int i1, int i2,
                                            vf2& o0, vf2& o1) {
  vf2 bb[N2], aa[N1];
#pragma unroll
  for (int j = 0; j < N2; ++j) bb[j] = s2r[i2 + j];
#pragma unroll
  for (int i = 0; i < N1; ++i) aa[i] = s1r[i1 + i];
  o0 = row_compute<N1, N2>(rowB, aa, bb);
  o1 = row_compute<N1, N2>(rowB + 256, aa, bb);
}

__global__ __launch_bounds__(512) void tp_kernel(
    const float* __restrict__ in1, const float* __restrict__ in2,
    const float* __restrict__ table, const int* __restrict__ meta,
    float* __restrict__ out) {
  __shared__ vf2 s1v[64 * SDIM];    // [batch_pair][dim], float2 = (b2t, b2t+1)
  __shared__ vf2 s2v[64 * SDIM];
  __shared__ float so[128 * SOH];   // [batch][local_h] quarter tile

  const int tid = threadIdx.x;
  const int b0 = blockIdx.x << 7;   // batch tile (128)
  const int h0 = blockIdx.y << 6;   // h tile (64)
  const int w = tid >> 6;           // wave id 0..7: rows (16q+2w, +1)
  const int t = tid & 63;           // lane = batch PAIR (2t, 2t+1)

  const int2* meta2 = reinterpret_cast<const int2*>(meta);
  int2 mcur = meta2[__builtin_amdgcn_readfirstlane((h0 >> 1) + w)];
  const unsigned long long tbase = (unsigned long long)(const void*)table;

  // ---- stage in1/in2 tiles, interleaving batch pairs into float2 ----
#pragma unroll
  for (int it = 0; it < 2; ++it) {
    int task = it * 512 + tid;         // 1024 tasks = 64 pairs x 16 float4
    int bp = task >> 4;                // batch pair 0..63
    int d4 = (task & 15) << 2;         // dim start
    const float* r0p = in1 + (size_t)(b0 + 2 * bp) * 64 + d4;
    const float* r1p = r0p + 64;
    float4 a0 = *reinterpret_cast<const float4*>(r0p);
    float4 a1 = *reinterpret_cast<const float4*>(r1p);
    vf2* p = &s1v[bp * SDIM + d4];
    vf2 u;
    u.x = a0.x; u.y = a1.x; p[0] = u;
    u.x = a0.y; u.y = a1.y; p[1] = u;
    u.x = a0.z; u.y = a1.z; p[2] = u;
    u.x = a0.w; u.y = a1.w; p[3] = u;
    const float* q0p = in2 + (size_t)(b0 + 2 * bp) * 64 + d4;
    const float* q1p = q0p + 64;
    float4 c0 = *reinterpret_cast<const float4*>(q0p);
    float4 c1 = *reinterpret_cast<const float4*>(q1p);
    vf2* p2 = &s2v[bp * SDIM + d4];
    u.x = c0.x; u.y = c1.x; p2[0] = u;
    u.x = c0.y; u.y = c1.y; p2[1] = u;
    u.x = c0.z; u.y = c1.z; p2[2] = u;
    u.x = c0.w; u.y = c1.w; p2[3] = u;
  }
  __syncthreads();

  const vf2* s1r = &s1v[t * SDIM];
  const vf2* s2r = &s2v[t * SDIM];

#pragma unroll 1
  for (int q = 0; q < 4; ++q) {
    // prefetch next quarter's meta (clamped on last iteration)
    int qn = (q < 3) ? (q + 1) : 0;
    int2 mnxt = meta2[__builtin_amdgcn_readfirstlane((h0 >> 1) + 8 * qn + w)];

    // wave-uniform byte address of this wave's row pair in the table
    unsigned rowoff = (unsigned)__builtin_amdgcn_readfirstlane(
        (int)((unsigned)(h0 + 16 * q + 2 * w) << 8));
    unsigned long long rowB = tbase + rowoff;

    int mm0 = mcur.x, mm1 = mcur.y;
    vf2 r0 = splat(0.f), r1 = splat(0.f);
    if (mm0 == mm1) {
      int i1 = mm0 & 255, i2 = (mm0 >> 8) & 255;
#define TP2_CASE(L1, L2) \
      case (L1 * 4 + L2): inner_tp2_s<2 * L1 + 1, 2 * L2 + 1>(rowB, s1r, s2r, i1, i2, r0, r1); break;
      switch (mm0 >> 16) {
        TP2_CASE(0, 0) TP2_CASE(0, 1) TP2_CASE(0, 2) TP2_CASE(0, 3)
        TP2_CASE(1, 0) TP2_CASE(1, 1) TP2_CASE(1, 2) TP2_CASE(1, 3)
        TP2_CASE(2, 0) TP2_CASE(2, 1) TP2_CASE(2, 2) TP2_CASE(2, 3)
        TP2_CASE(3, 0) TP2_CASE(3, 1) TP2_CASE(3, 2) TP2_CASE(3, 3)
        default: break;
      }
#undef TP2_CASE
    } else {
#define TP_CASE(L1, L2, ADDR, DST, MI1, MI2) \
      case (L1 * 4 + L2): DST = inner_tp_s<2 * L1 + 1, 2 * L2 + 1>(ADDR, s1r, s2r, MI1, MI2); break;
      {
        int i1 = mm0 & 255, i2 = (mm0 >> 8) & 255;
        switch (mm0 >> 16) {
          TP_CASE(0, 0, rowB, r0, i1, i2) TP_CASE(0, 1, rowB, r0, i1, i2)
          TP_CASE(0, 2, rowB, r0, i1, i2) TP_CASE(0, 3, rowB, r0, i1, i2)
          TP_CASE(1, 0, rowB, r0, i1, i2) TP_CASE(1, 1, rowB, r0, i1, i2)
          TP_CASE(1, 2, rowB, r0, i1, i2) TP_CASE(1, 3, rowB, r0, i1, i2)
          TP_CASE(2, 0, rowB, r0, i1, i2) TP_CASE(2, 1, rowB, r0, i1, i2)
          TP_CASE(2, 2, rowB, r0, i1, i2) TP_CASE(2, 3, rowB, r0, i1, i2)
          TP_CASE(3, 0, rowB, r0, i1, i2) TP_CASE(3, 1, rowB, r0, i1, i2)
          TP_CASE(3, 2, rowB, r0, i1, i2) TP_CASE(3, 3, rowB, r0, i1, i2)
          default: break;
        }
      }
      {
        int i1 = mm1 & 255, i2 = (mm1 >> 8) & 255;
        unsigned long long rowC = rowB + 256;
        switch (mm1 >> 16) {
          TP_CASE(0, 0, rowC, r1, i1, i2) TP_CASE(0, 1, rowC, r1, i1, i2)
          TP_CASE(0, 2, rowC, r1, i1, i2) TP_CASE(0, 3, rowC, r1, i1, i2)
          TP_CASE(1, 0, rowC, r1, i1, i2) TP_CASE(1, 1, rowC, r1, i1, i2)
          TP_CASE(1, 2, rowC, r1, i1, i2) TP_CASE(1, 3, rowC, r1, i1, i2)
          TP_CASE(2, 0, rowC, r1, i1, i2) TP_CASE(2, 1, rowC, r1, i1, i2)
          TP_CASE(2, 2, rowC, r1, i1, i2) TP_CASE(2, 3, rowC, r1, i1, i2)
          TP_CASE(3, 0, rowC, r1, i1, i2) TP_CASE(3, 1, rowC, r1, i1, i2)
          TP_CASE(3, 2, rowC, r1, i1, i2) TP_CASE(3, 3, rowC, r1, i1, i2)
          default: break;
        }
      }
#undef TP_CASE
    }
    // so[batch][local_h]: r0 = row h_a {b2t, b2t+1}, r1 = row h_b
    {
      float* sa = &so[(2 * t) * SOH + 2 * w];
      sa[0] = r0.x; sa[1] = r1.x;
      float* sb = &so[(2 * t + 1) * SOH + 2 * w];
      sb[0] = r0.y; sb[1] = r1.y;
    }
    __syncthreads();

    // ---- flush quarter: 16 h x 128 b; 512 threads x float4 ----
    {
      int b = tid >> 2;                // batch row 0..127
      int hs = (tid & 3) << 2;         // h offset 0,4,8,12
      const float* sp = &so[b * SOH + hs];
      float4 v;
      v.x = sp[0]; v.y = sp[1]; v.z = sp[2]; v.w = sp[3];
      *reinterpret_cast<float4*>(out + (size_t)(b0 + b) * 4096 + h0 + 16 * q + hs) = v;
    }
    if (q < 3) __syncthreads();   // so reused next quarter
    mcur = mnxt;
  }
}

extern "C" void kernel_launch(void* const* d_in, const int* in_sizes, int n_in,
                              void* d_out, int out_size, void* d_ws, size_t ws_size,
                              hipStream_t stream) {
  const float* in1 = (const float*)d_in[0];
  const float* in2 = (const float*)d_in[1];
  const float* cb  = (const float*)d_in[2];
  float* out = (float*)d_out;
  float* table = (float*)d_ws;                       // 4096*64*4 = 1 MB
  int* meta = (int*)((char*)d_ws + (size_t)4096 * 64 * 4);   // +16 KB
  (void)in_sizes; (void)n_in; (void)out_size; (void)ws_size;
  prep_kernel<<<1024, 256, 0, stream>>>(cb, table, meta);
  tp_kernel<<<dim3(32, 64), 512, 0, stream>>>(in1, in2, table, meta, out);
}